// Round 2
// baseline (564.183 us; speedup 1.0000x reference)
//
#include <hip/hip_runtime.h>
#include <hip/hip_bf16.h>

typedef unsigned short u16;
typedef __bf16 bf16x8 __attribute__((ext_vector_type(8)));
typedef u16 u16x8 __attribute__((ext_vector_type(8)));
typedef float f32x4 __attribute__((ext_vector_type(4)));

__device__ __forceinline__ float bf2f(u16 u) {
    return __uint_as_float(((unsigned)u) << 16);
}
__device__ __forceinline__ u16 f2bf(float f) {
    unsigned u = __float_as_uint(f);
    unsigned r = (u + 0x7fffu + ((u >> 16) & 1u)) >> 16;
    return (u16)r;
}

// ---------------- fp32 -> bf16 bulk convert (8 elems/thread) ----------------
__global__ __launch_bounds__(256) void f32_to_bf16(const float* __restrict__ in,
                                                   u16* __restrict__ out, int n) {
    int i = (blockIdx.x * 256 + threadIdx.x) * 8;
    if (i + 8 > n) return;
    float4 a = *(const float4*)&in[i];
    float4 b = *(const float4*)&in[i + 4];
    u16x8 o;
    o[0] = f2bf(a.x); o[1] = f2bf(a.y); o[2] = f2bf(a.z); o[3] = f2bf(a.w);
    o[4] = f2bf(b.x); o[5] = f2bf(b.y); o[6] = f2bf(b.z); o[7] = f2bf(b.w);
    *(u16x8*)&out[i] = o;
}

// ---------------- transpose+convert: W fp32 [K][N] -> WT bf16 [N][K] ----------------
__global__ __launch_bounds__(256) void transpose_f32_bf16(const float* __restrict__ W,
                                                          u16* __restrict__ WT,
                                                          int K, int N) {
    __shared__ float tile[64][65];
    const int nt = N >> 6;
    const int k0 = (blockIdx.x / nt) << 6;
    const int n0 = (blockIdx.x % nt) << 6;
    for (int i = threadIdx.x; i < 4096; i += 256) {
        int r = i >> 6, c = i & 63;
        tile[r][c] = W[(size_t)(k0 + r) * N + n0 + c];
    }
    __syncthreads();
    for (int i = threadIdx.x; i < 4096; i += 256) {
        int r = i >> 6, c = i & 63;
        WT[(size_t)(n0 + r) * K + k0 + c] = f2bf(tile[c][r]);
    }
}

// ---------------- MFMA GEMM: C[M][N] = rowmap(A)[M][K] @ Bt[N][K]^T (+bias) ----------
// A, Bt are bf16. MODE 0: row r -> r (guard). MODE 1: r -> (r/256)*257+(r%256)+1.
// MODE 2: r -> r*257 (guard). OUTF: store float (+bias), else bf16.
template <int MODE, int OUTF>
__global__ __launch_bounds__(256) void gemm_k(const u16* __restrict__ A,
                                              const u16* __restrict__ Bt,
                                              void* __restrict__ Cv,
                                              const float* __restrict__ bias,
                                              int M, int N, int K) {
    __shared__ u16 As[128][72];
    __shared__ u16 Bs[128][72];
    const int t = threadIdx.x;
    const int bn0 = blockIdx.x * 128;
    const int bm0 = blockIdx.y * 128;
    const int wave = t >> 6, lane = t & 63;
    const int wm = (wave >> 1) * 64, wn = (wave & 1) * 64;
    const int lr = lane & 15, lh = lane >> 4;

    f32x4 acc[4][4] = {};

    for (int kt = 0; kt < K; kt += 64) {
        __syncthreads();
#pragma unroll
        for (int i = 0; i < 4; i++) {
            int c = i * 256 + t;        // 0..1023
            int row = c >> 3, seg = c & 7;
            int r = bm0 + row;
            long g;
            if (MODE == 0)      g = (r < M) ? (long)r : 0l;
            else if (MODE == 1) g = (long)(r >> 8) * 257 + (r & 255) + 1;
            else                g = (r < M) ? (long)r * 257 : 0l;
            *(bf16x8*)&As[row][seg * 8] =
                *(const bf16x8*)&A[g * K + kt + seg * 8];
            long nr = bn0 + row;
            *(bf16x8*)&Bs[row][seg * 8] =
                *(const bf16x8*)&Bt[nr * K + kt + seg * 8];
        }
        __syncthreads();
#pragma unroll
        for (int kk = 0; kk < 2; kk++) {
            bf16x8 af[4], bfr[4];
#pragma unroll
            for (int mi = 0; mi < 4; mi++)
                af[mi] = *(const bf16x8*)&As[wm + mi * 16 + lr][kk * 32 + lh * 8];
#pragma unroll
            for (int ni = 0; ni < 4; ni++)
                bfr[ni] = *(const bf16x8*)&Bs[wn + ni * 16 + lr][kk * 32 + lh * 8];
#pragma unroll
            for (int mi = 0; mi < 4; mi++)
#pragma unroll
                for (int ni = 0; ni < 4; ni++)
                    acc[mi][ni] = __builtin_amdgcn_mfma_f32_16x16x32_bf16(
                        af[mi], bfr[ni], acc[mi][ni], 0, 0, 0);
        }
    }

#pragma unroll
    for (int mi = 0; mi < 4; mi++) {
#pragma unroll
        for (int ni = 0; ni < 4; ni++) {
#pragma unroll
            for (int r2 = 0; r2 < 4; r2++) {
                int m = bm0 + wm + mi * 16 + lh * 4 + r2;
                if (m < M) {
                    int nc = bn0 + wn + ni * 16 + lr;
                    float v = acc[mi][ni][r2];
                    if (OUTF) {
                        ((float*)Cv)[(size_t)m * N + nc] = v + bias[nc];
                    } else {
                        ((u16*)Cv)[(size_t)m * N + nc] = f2bf(v);
                    }
                }
            }
        }
    }
}

// ---------------- attention av: qa(5x64) @ kv(1280x64)^T -> softmax -> @ vv ----------
// one block per (bi,hd); 320 threads = 5 waves
__global__ __launch_bounds__(320) void attn_av(const u16* __restrict__ vqkv,
                                               const u16* __restrict__ aqkv,
                                               u16* __restrict__ cat) {
    __shared__ float qa[5][64];
    __shared__ float p[5][1280];
    const int bi = blockIdx.x >> 3, hd = blockIdx.x & 7;
    const int t = threadIdx.x;
    {
        int tt = t >> 6, d = t & 63;
        qa[tt][d] = bf2f(aqkv[(size_t)(bi * 5 + tt) * 1536 + hd * 64 + d]);
    }
    __syncthreads();
    // phase 1: scores
    for (int s = t; s < 1280; s += 320) {
        int j = s / 5, t5 = s - j * 5;
        const u16* row = &vqkv[(size_t)((bi * 5 + t5) * 256 + j) * 1536 + 512 + hd * 64];
        float a0 = 0, a1 = 0, a2 = 0, a3 = 0, a4 = 0;
#pragma unroll
        for (int d = 0; d < 64; d += 8) {
            u16x8 v8 = *(const u16x8*)&row[d];
#pragma unroll
            for (int jj = 0; jj < 8; jj++) {
                float f = bf2f(v8[jj]);
                a0 += f * qa[0][d + jj];
                a1 += f * qa[1][d + jj];
                a2 += f * qa[2][d + jj];
                a3 += f * qa[3][d + jj];
                a4 += f * qa[4][d + jj];
            }
        }
        p[0][s] = a0 * 0.125f; p[1][s] = a1 * 0.125f; p[2][s] = a2 * 0.125f;
        p[3][s] = a3 * 0.125f; p[4][s] = a4 * 0.125f;
    }
    __syncthreads();
    const int wave = t >> 6, lane = t & 63;
    // phase 2: softmax, wave w handles row w
    {
        float mx = -3.4e38f;
        for (int s = lane; s < 1280; s += 64) mx = fmaxf(mx, p[wave][s]);
#pragma unroll
        for (int off = 32; off > 0; off >>= 1) mx = fmaxf(mx, __shfl_xor(mx, off));
        float sum = 0.f;
        for (int s = lane; s < 1280; s += 64) {
            float e = __expf(p[wave][s] - mx);
            p[wave][s] = e;
            sum += e;
        }
#pragma unroll
        for (int off = 32; off > 0; off >>= 1) sum += __shfl_xor(sum, off);
        float inv = 1.f / sum;
        for (int s = lane; s < 1280; s += 64) p[wave][s] *= inv;
    }
    __syncthreads();
    // phase 3: out[t][d] = sum_s p[t][s] * vv[s][d]; thread = (wave=t, lane=d)
    float acc = 0.f;
    const size_t colo = 1024 + hd * 64 + lane;
    for (int j = 0; j < 256; j++) {
#pragma unroll
        for (int t5 = 0; t5 < 5; t5++) {
            acc += p[wave][j * 5 + t5] *
                   bf2f(vqkv[(size_t)((bi * 5 + t5) * 256 + j) * 1536 + colo]);
        }
    }
    cat[(size_t)((bi * 5 + wave) * 257) * 512 + hd * 64 + lane] = f2bf(acc);
}

// ---------------- attention va: (qv*m)(1280x64) @ ka(5x64)^T -> softmax5 -> @ va -----
// one block per (bi,hd); 256 threads = 4 waves, wave handles query s strided
__global__ __launch_bounds__(256) void attn_va(const u16* __restrict__ vqkv,
                                               const u16* __restrict__ aqkv,
                                               const float* __restrict__ mask,
                                               u16* __restrict__ cat) {
    __shared__ float ka[5][64], vaS[5][64];
    const int bi = blockIdx.x >> 3, hd = blockIdx.x & 7;
    const int t = threadIdx.x;
    for (int i = t; i < 320; i += 256) {
        int tt = i >> 6, d = i & 63;
        ka[tt][d]  = bf2f(aqkv[(size_t)(bi * 5 + tt) * 1536 + 512 + hd * 64 + d]);
        vaS[tt][d] = bf2f(aqkv[(size_t)(bi * 5 + tt) * 1536 + 1024 + hd * 64 + d]);
    }
    __syncthreads();
    const int wave = t >> 6, lane = t & 63;
    for (int s = wave; s < 1280; s += 4) {
        int j = s / 5, t5 = s - j * 5;
        size_t xr = (size_t)((bi * 5 + t5) * 256 + j) * 1536;
        float m = mask[(bi * 5 + t5) * 256 + j];
        float q = bf2f(vqkv[xr + hd * 64 + lane]) * m;
        float r0 = q * ka[0][lane], r1 = q * ka[1][lane], r2 = q * ka[2][lane];
        float r3 = q * ka[3][lane], r4 = q * ka[4][lane];
#pragma unroll
        for (int off = 32; off > 0; off >>= 1) {
            r0 += __shfl_xor(r0, off);
            r1 += __shfl_xor(r1, off);
            r2 += __shfl_xor(r2, off);
            r3 += __shfl_xor(r3, off);
            r4 += __shfl_xor(r4, off);
        }
        r0 *= 0.125f; r1 *= 0.125f; r2 *= 0.125f; r3 *= 0.125f; r4 *= 0.125f;
        float mx = fmaxf(fmaxf(fmaxf(r0, r1), fmaxf(r2, r3)), r4);
        float e0 = __expf(r0 - mx), e1 = __expf(r1 - mx), e2 = __expf(r2 - mx);
        float e3 = __expf(r3 - mx), e4 = __expf(r4 - mx);
        float inv = 1.f / (e0 + e1 + e2 + e3 + e4);
        float o = (e0 * vaS[0][lane] + e1 * vaS[1][lane] + e2 * vaS[2][lane] +
                   e3 * vaS[3][lane] + e4 * vaS[4][lane]) * inv;
        cat[((size_t)((bi * 5 + t5) * 257) + 1 + j) * 512 + hd * 64 + lane] = f2bf(o);
    }
}

extern "C" void kernel_launch(void* const* d_in, const int* in_sizes, int n_in,
                              void* d_out, int out_size, void* d_ws, size_t ws_size,
                              hipStream_t stream) {
    const float* x    = (const float*)d_in[0];  // (160,257,512) f32
    const float* mask = (const float*)d_in[1];  // (160,256) f32
    const float* Wv   = (const float*)d_in[2];  // (512,1536) f32
    const float* Wa   = (const float*)d_in[3];  // (512,1536) f32
    const float* Wo   = (const float*)d_in[4];  // (512,512) f32
    const float* bo   = (const float*)d_in[5];  // (512,) f32
    float* out = (float*)d_out;

    char* ws = (char*)d_ws;
    u16* xb   = (u16*)(ws);                   // 41120*512*2 = 42,106,880 B
    u16* WvT  = (u16*)(ws + 42106880);        // 1,572,864 B
    u16* WaT  = (u16*)(ws + 43679744);        // 1,572,864 B
    u16* WoT  = (u16*)(ws + 45252608);        //   524,288 B
    u16* aqkv = (u16*)(ws + 45776896);        //   491,520 B
    u16* vqkv = (u16*)(ws + 46268416);        // 40960*1536*2 = 125,829,120 B
    u16* cat  = (u16*)(ws + 172097536);       // 42,106,880 B  -> total ~214.2 MB

    // convert x (all 41120 rows) to bf16
    f32_to_bf16<<<dim3(10280), 256, 0, stream>>>(x, xb, 41120 * 512);
    transpose_f32_bf16<<<dim3(192), 256, 0, stream>>>(Wv, WvT, 512, 1536);
    transpose_f32_bf16<<<dim3(192), 256, 0, stream>>>(Wa, WaT, 512, 1536);
    transpose_f32_bf16<<<dim3(64),  256, 0, stream>>>(Wo, WoT, 512, 512);

    // v_qkv = V @ Wv_qkv   (V rows = xb[i*257 + 1 + j])
    gemm_k<1, 0><<<dim3(12, 320), 256, 0, stream>>>(xb, WvT, vqkv, nullptr, 40960, 1536, 512);
    // a_qkv = A @ Wa_qkv   (A rows = xb[i*257])
    gemm_k<2, 0><<<dim3(12, 2), 256, 0, stream>>>(xb, WaT, aqkv, nullptr, 160, 1536, 512);

    attn_av<<<dim3(256), 320, 0, stream>>>(vqkv, aqkv, cat);
    attn_va<<<dim3(256), 256, 0, stream>>>(vqkv, aqkv, mask, cat);

    // out = cat @ Wo + bo   (float out)
    gemm_k<0, 1><<<dim3(4, 322), 256, 0, stream>>>(cat, WoT, out, bo, 41120, 512, 512);
}

// Round 4
// 388.643 us; speedup vs baseline: 1.4517x; 1.4517x over previous
//
#include <hip/hip_runtime.h>
#include <hip/hip_bf16.h>

typedef unsigned short u16;
typedef __bf16 bf16x8 __attribute__((ext_vector_type(8)));
typedef u16 u16x8 __attribute__((ext_vector_type(8)));
typedef float f32x4 __attribute__((ext_vector_type(4)));

__device__ __forceinline__ float bf2f(u16 u) {
    return __uint_as_float(((unsigned)u) << 16);
}
__device__ __forceinline__ u16 f2bf(float f) {
    unsigned u = __float_as_uint(f);
    unsigned r = (u + 0x7fffu + ((u >> 16) & 1u)) >> 16;
    return (u16)r;
}

// async global->LDS, 16B per lane. dst is wave-uniform base; HW adds lane*16.
__device__ __forceinline__ void gl_lds16(const u16* g, u16* l) {
    __builtin_amdgcn_global_load_lds(
        (const __attribute__((address_space(1))) void*)g,
        (__attribute__((address_space(3))) void*)l, 16, 0, 0);
}

// ---------------- fp32 -> bf16 bulk convert (8 elems/thread) ----------------
__global__ __launch_bounds__(256) void f32_to_bf16(const float* __restrict__ in,
                                                   u16* __restrict__ out, int n) {
    int i = (blockIdx.x * 256 + threadIdx.x) * 8;
    if (i + 8 > n) return;
    float4 a = *(const float4*)&in[i];
    float4 b = *(const float4*)&in[i + 4];
    u16x8 o;
    o[0] = f2bf(a.x); o[1] = f2bf(a.y); o[2] = f2bf(a.z); o[3] = f2bf(a.w);
    o[4] = f2bf(b.x); o[5] = f2bf(b.y); o[6] = f2bf(b.z); o[7] = f2bf(b.w);
    *(u16x8*)&out[i] = o;
}

// ---------------- transpose+convert: W fp32 [K][N] -> WT bf16 [N][K] ----------------
__global__ __launch_bounds__(256) void transpose_f32_bf16(const float* __restrict__ W,
                                                          u16* __restrict__ WT,
                                                          int K, int N) {
    __shared__ float tile[64][65];
    const int nt = N >> 6;
    const int k0 = (blockIdx.x / nt) << 6;
    const int n0 = (blockIdx.x % nt) << 6;
    for (int i = threadIdx.x; i < 4096; i += 256) {
        int r = i >> 6, c = i & 63;
        tile[r][c] = W[(size_t)(k0 + r) * N + n0 + c];
    }
    __syncthreads();
    for (int i = threadIdx.x; i < 4096; i += 256) {
        int r = i >> 6, c = i & 63;
        WT[(size_t)(n0 + r) * K + k0 + c] = f2bf(tile[c][r]);
    }
}

// ---------------- MFMA GEMM: C[M][N] = rowmap(A)[M][K] @ Bt[N][K]^T (+bias) ----------
// m97 structure: 128x128 tile, BK=64, global_load_lds width 16, linear LDS.
// MODE 0: row r -> r (clamp). MODE 1: r -> (r/256)*257+(r%256)+1 (exact).
// MODE 2: r -> r*257 (clamp). OUTF: store float (+bias), else bf16.
template <int MODE, int OUTF>
__global__ __launch_bounds__(256) void gemm_k(const u16* __restrict__ A,
                                              const u16* __restrict__ Bt,
                                              void* __restrict__ Cv,
                                              const float* __restrict__ bias,
                                              int M, int N, int K) {
    __shared__ u16 As[128][64];
    __shared__ u16 Bs[128][64];
    const int t = threadIdx.x;
    const int bn0 = blockIdx.x * 128;
    const int bm0 = blockIdx.y * 128;
    const int wave = t >> 6, lane = t & 63;
    const int wm = (wave >> 1) * 64, wn = (wave & 1) * 64;
    const int lr = lane & 15, lh = lane >> 4;

    // staging geometry: issue i covers rows i*32 + wave*8 + (lane>>3), col (lane&7)*8
    const int srow = wave * 8 + (lane >> 3);
    const int scol = (lane & 7) * 8;

    f32x4 acc[4][4] = {};

    for (int kt = 0; kt < K; kt += 64) {
        __syncthreads();
#pragma unroll
        for (int i = 0; i < 4; i++) {
            int row = i * 32 + srow;
            int r = bm0 + row;
            long g;
            if (MODE == 0)      g = (r < M) ? (long)r : 0l;
            else if (MODE == 1) g = (long)(r >> 8) * 257 + (r & 255) + 1;
            else                g = (r < M) ? (long)r * 257 : 0l;
            gl_lds16(&A[g * K + kt + scol], &As[0][0] + i * 2048 + wave * 512);
            long nr = bn0 + row;
            gl_lds16(&Bt[nr * K + kt + scol], &Bs[0][0] + i * 2048 + wave * 512);
        }
        __syncthreads();
#pragma unroll
        for (int kk = 0; kk < 2; kk++) {
            bf16x8 af[4], bfr[4];
#pragma unroll
            for (int mi = 0; mi < 4; mi++)
                af[mi] = *(const bf16x8*)&As[wm + mi * 16 + lr][kk * 32 + lh * 8];
#pragma unroll
            for (int ni = 0; ni < 4; ni++)
                bfr[ni] = *(const bf16x8*)&Bs[wn + ni * 16 + lr][kk * 32 + lh * 8];
#pragma unroll
            for (int mi = 0; mi < 4; mi++)
#pragma unroll
                for (int ni = 0; ni < 4; ni++)
                    acc[mi][ni] = __builtin_amdgcn_mfma_f32_16x16x32_bf16(
                        af[mi], bfr[ni], acc[mi][ni], 0, 0, 0);
        }
    }

#pragma unroll
    for (int mi = 0; mi < 4; mi++) {
#pragma unroll
        for (int ni = 0; ni < 4; ni++) {
#pragma unroll
            for (int r2 = 0; r2 < 4; r2++) {
                int m = bm0 + wm + mi * 16 + lh * 4 + r2;
                if (m < M) {
                    int nc = bn0 + wn + ni * 16 + lr;
                    float v = acc[mi][ni][r2];
                    if (OUTF) {
                        ((float*)Cv)[(size_t)m * N + nc] = v + bias[nc];
                    } else {
                        ((u16*)Cv)[(size_t)m * N + nc] = f2bf(v);
                    }
                }
            }
        }
    }
}

// ---------------- attention av: qa(5x64) @ kv(1280x64)^T -> softmax -> @ vv ----------
// one block per (bi,hd), bi in [0,32); 320 threads = 5 waves
__global__ __launch_bounds__(320) void attn_av(const u16* __restrict__ vqkv,
                                               const u16* __restrict__ aqkv,
                                               u16* __restrict__ cat) {
    __shared__ float qa[5][64];
    __shared__ float p[5][1280];
    const int bi = blockIdx.x >> 3, hd = blockIdx.x & 7;
    const int t = threadIdx.x;
    {
        int tt = t >> 6, d = t & 63;
        qa[tt][d] = bf2f(aqkv[(size_t)(bi * 5 + tt) * 1536 + hd * 64 + d]);
    }
    __syncthreads();
    // phase 1: scores
    for (int s = t; s < 1280; s += 320) {
        int j = s / 5, t5 = s - j * 5;
        const u16* row = &vqkv[(size_t)((bi * 5 + t5) * 256 + j) * 1536 + 512 + hd * 64];
        float a0 = 0, a1 = 0, a2 = 0, a3 = 0, a4 = 0;
#pragma unroll
        for (int d = 0; d < 64; d += 8) {
            u16x8 v8 = *(const u16x8*)&row[d];
#pragma unroll
            for (int jj = 0; jj < 8; jj++) {
                float f = bf2f(v8[jj]);
                a0 += f * qa[0][d + jj];
                a1 += f * qa[1][d + jj];
                a2 += f * qa[2][d + jj];
                a3 += f * qa[3][d + jj];
                a4 += f * qa[4][d + jj];
            }
        }
        p[0][s] = a0 * 0.125f; p[1][s] = a1 * 0.125f; p[2][s] = a2 * 0.125f;
        p[3][s] = a3 * 0.125f; p[4][s] = a4 * 0.125f;
    }
    __syncthreads();
    const int wave = t >> 6, lane = t & 63;
    // phase 2: softmax, wave w handles row w
    {
        float mx = -3.4e38f;
        for (int s = lane; s < 1280; s += 64) mx = fmaxf(mx, p[wave][s]);
#pragma unroll
        for (int off = 32; off > 0; off >>= 1) mx = fmaxf(mx, __shfl_xor(mx, off));
        float sum = 0.f;
        for (int s = lane; s < 1280; s += 64) {
            float e = __expf(p[wave][s] - mx);
            p[wave][s] = e;
            sum += e;
        }
#pragma unroll
        for (int off = 32; off > 0; off >>= 1) sum += __shfl_xor(sum, off);
        float inv = 1.f / sum;
        for (int s = lane; s < 1280; s += 64) p[wave][s] *= inv;
    }
    __syncthreads();
    // phase 3: out[t][d] = sum_s p[t][s] * vv[s][d]; thread = (wave=t, lane=d)
    float acc = 0.f;
    const size_t colo = 1024 + hd * 64 + lane;
    for (int j = 0; j < 256; j++) {
#pragma unroll
        for (int t5 = 0; t5 < 5; t5++) {
            acc += p[wave][j * 5 + t5] *
                   bf2f(vqkv[(size_t)((bi * 5 + t5) * 256 + j) * 1536 + colo]);
        }
    }
    cat[(size_t)((bi * 5 + wave) * 257) * 512 + hd * 64 + lane] = f2bf(acc);
}

// ---------------- attention va: thread-per-query, no cross-lane ops -----------------
// grid 1280 = 5 chunks x (32 bi x 8 hd); each thread owns one query s = chunk*256 + tid
__global__ __launch_bounds__(256) void attn_va(const u16* __restrict__ vqkv,
                                               const u16* __restrict__ aqkv,
                                               const float* __restrict__ mask,
                                               u16* __restrict__ cat) {
    __shared__ float ka[5][64], vaS[5][64];
    const int blk = blockIdx.x;
    const int chunk = blk % 5;
    const int bh = blk / 5;                 // 0..255
    const int bi = bh >> 3, hd = bh & 7;    // bi in [0,32)
    const int t = threadIdx.x;
    for (int i = t; i < 320; i += 256) {
        int tt = i >> 6, d = i & 63;
        ka[tt][d]  = bf2f(aqkv[(size_t)(bi * 5 + tt) * 1536 + 512 + hd * 64 + d]);
        vaS[tt][d] = bf2f(aqkv[(size_t)(bi * 5 + tt) * 1536 + 1024 + hd * 64 + d]);
    }
    __syncthreads();
    const int s = chunk * 256 + t;          // 0..1279
    const int j = s / 5, t5 = s - j * 5;
    const int row = (bi * 5 + t5) * 256 + j;
    const u16* qrow = &vqkv[(size_t)row * 1536 + hd * 64];
    float r0 = 0, r1 = 0, r2 = 0, r3 = 0, r4 = 0;
#pragma unroll
    for (int d = 0; d < 64; d += 8) {
        u16x8 q8 = *(const u16x8*)&qrow[d];
#pragma unroll
        for (int jj = 0; jj < 8; jj++) {
            float f = bf2f(q8[jj]);
            r0 += f * ka[0][d + jj];
            r1 += f * ka[1][d + jj];
            r2 += f * ka[2][d + jj];
            r3 += f * ka[3][d + jj];
            r4 += f * ka[4][d + jj];
        }
    }
    const float mval = mask[row] * 0.125f;
    r0 *= mval; r1 *= mval; r2 *= mval; r3 *= mval; r4 *= mval;
    float mx = fmaxf(fmaxf(fmaxf(r0, r1), fmaxf(r2, r3)), r4);
    float e0 = __expf(r0 - mx), e1 = __expf(r1 - mx), e2 = __expf(r2 - mx);
    float e3 = __expf(r3 - mx), e4 = __expf(r4 - mx);
    const float inv = 1.f / (e0 + e1 + e2 + e3 + e4);
    e0 *= inv; e1 *= inv; e2 *= inv; e3 *= inv; e4 *= inv;
    const size_t orow = ((size_t)((bi * 5 + t5) * 257) + 1 + j) * 512 + hd * 64;
#pragma unroll
    for (int d = 0; d < 64; d += 8) {
        u16x8 o8;
#pragma unroll
        for (int jj = 0; jj < 8; jj++) {
            float o = e0 * vaS[0][d + jj] + e1 * vaS[1][d + jj] + e2 * vaS[2][d + jj] +
                      e3 * vaS[3][d + jj] + e4 * vaS[4][d + jj];
            o8[jj] = f2bf(o);
        }
        *(u16x8*)&cat[orow + d] = o8;
    }
}

extern "C" void kernel_launch(void* const* d_in, const int* in_sizes, int n_in,
                              void* d_out, int out_size, void* d_ws, size_t ws_size,
                              hipStream_t stream) {
    const float* x    = (const float*)d_in[0];  // (160,257,512) f32
    const float* mask = (const float*)d_in[1];  // (160,256) f32
    const float* Wv   = (const float*)d_in[2];  // (512,1536) f32
    const float* Wa   = (const float*)d_in[3];  // (512,1536) f32
    const float* Wo   = (const float*)d_in[4];  // (512,512) f32
    const float* bo   = (const float*)d_in[5];  // (512,) f32
    float* out = (float*)d_out;

    char* ws = (char*)d_ws;
    u16* xb   = (u16*)(ws);                   // 41120*512*2 = 42,106,880 B
    u16* WvT  = (u16*)(ws + 42106880);        // 1,572,864 B
    u16* WaT  = (u16*)(ws + 43679744);        // 1,572,864 B
    u16* WoT  = (u16*)(ws + 45252608);        //   524,288 B
    u16* aqkv = (u16*)(ws + 45776896);        //   491,520 B
    u16* vqkv = (u16*)(ws + 46268416);        // 40960*1536*2 = 125,829,120 B
    u16* cat  = (u16*)(ws + 172097536);       // 42,106,880 B  -> total ~214.2 MB

    f32_to_bf16<<<dim3(10280), 256, 0, stream>>>(x, xb, 41120 * 512);
    transpose_f32_bf16<<<dim3(192), 256, 0, stream>>>(Wv, WvT, 512, 1536);
    transpose_f32_bf16<<<dim3(192), 256, 0, stream>>>(Wa, WaT, 512, 1536);
    transpose_f32_bf16<<<dim3(64),  256, 0, stream>>>(Wo, WoT, 512, 512);

    // v_qkv = V @ Wv_qkv   (V rows = xb[i*257 + 1 + j])
    gemm_k<1, 0><<<dim3(12, 320), 256, 0, stream>>>(xb, WvT, vqkv, nullptr, 40960, 1536, 512);
    // a_qkv = A @ Wa_qkv   (A rows = xb[i*257])
    gemm_k<2, 0><<<dim3(12, 2), 256, 0, stream>>>(xb, WaT, aqkv, nullptr, 160, 1536, 512);

    attn_av<<<dim3(256), 320, 0, stream>>>(vqkv, aqkv, cat);
    attn_va<<<dim3(1280), 256, 0, stream>>>(vqkv, aqkv, mask, cat);

    // out = cat @ Wo + bo   (float out)
    gemm_k<0, 1><<<dim3(4, 322), 256, 0, stream>>>(cat, WoT, out, bo, 41120, 512, 512);
}